// Round 6
// baseline (139.572 us; speedup 1.0000x reference)
//
#include <hip/hip_runtime.h>
#include <hip/hip_bf16.h>
#include <math.h>

#define NH 4
#define DK 32
#define CC 128
#define HW 56
#define SHIFT 3
#define NTOK 12544   // 4*56*56 == 256*49
#define S_GLB 3136
#define VTW_STRIDE 12608
#define SCALE_L2E 0.25503488f  // log2(e)/sqrt(32): exp2-domain softmax scale

typedef unsigned short u16;
typedef short bf16x8 __attribute__((ext_vector_type(8)));
typedef unsigned short u16x8 __attribute__((ext_vector_type(8)));
typedef float f32x4 __attribute__((ext_vector_type(4)));

static __device__ __forceinline__ u16 f2bf(float f) {
  unsigned int b = __builtin_bit_cast(unsigned int, f);
  return (u16)((b + 0x7FFFu + ((b >> 16) & 1u)) >> 16);
}
static __device__ __forceinline__ unsigned pk2bf(float a, float b) {
  unsigned r;
  asm("v_cvt_pk_bf16_f32 %0, %1, %2" : "=v"(r) : "v"(a), "v"(b));
  return r;
}
static __device__ __forceinline__ float fexp2(float x) {
  float r;
  asm("v_exp_f32 %0, %1" : "=v"(r) : "v"(x));
  return r;
}
static __device__ __forceinline__ void gload16(const void* g, void* l) {
  __builtin_amdgcn_global_load_lds(
      (const __attribute__((address_space(1))) unsigned int*)g,
      (__attribute__((address_space(3))) unsigned int*)l, 16, 0, 0);
}

// ---------------- all weight converts in one kernel
__global__ __launch_bounds__(256) void cvt_all_k(
    const float* __restrict__ w1, const float* __restrict__ w2,
    const float* __restrict__ wq, const float* __restrict__ wk,
    const float* __restrict__ wv, const float* __restrict__ wo,
    u16* __restrict__ w1t, u16* __restrict__ w2t,
    u16* __restrict__ wqkvt, u16* __restrict__ wot) {
  const int idx = blockIdx.x * 256 + threadIdx.x;
  if (idx < 65536) {            // w1 [128][512] -> w1t [512][128]
    const int c = idx >> 7, r = idx & 127;
    w1t[idx] = f2bf(w1[r * 512 + c]);
  } else if (idx < 131072) {    // w2 [512][128] -> w2t [128][512]
    const int o = idx - 65536;
    const int c = o / 512, r = o - c * 512;
    w2t[o] = f2bf(w2[r * 128 + c]);
  } else {                      // four 128x128 -> transposed
    const int o = idx - 131072;
    const int which = o >> 14, oo = o & 16383;
    const int c = oo >> 7, r = oo & 127;
    const float* src = (which == 0) ? wq : (which == 1) ? wk : (which == 2) ? wv : wo;
    u16* dst = (which < 3) ? (wqkvt + which * 16384) : wot;
    dst[oo] = f2bf(src[r * 128 + c]);
  }
}

// ---------------- shift + window-partition gather -> bf16 [t_w][128]
__global__ __launch_bounds__(256) void win_gather_k(
    const float* __restrict__ x, u16* __restrict__ xg) {
  const int t = blockIdx.x * 2 + (threadIdx.x >> 7);
  const int c = threadIdx.x & 127;
  const int win = t / 49, tok = t % 49;
  const int b = win >> 6, wrem = win & 63;
  const int wi = wrem >> 3, wj = wrem & 7;
  const int i = tok / 7, j = tok % 7;
  int hh = wi * 7 + i + SHIFT; if (hh >= HW) hh -= HW;
  int ww = wj * 7 + j + SHIFT; if (ww >= HW) ww -= HW;
  xg[(size_t)t * CC + c] = f2bf(x[((size_t)(b * HW + hh) * HW + ww) * CC + c]);
}

// ---------------- fused QKV GEMM. PATH 0: window layout (bf16 in),
// PATH 1: global layout with fused LN1 (fp32 in).
template <int PATH>
__global__ __launch_bounds__(256) void qkv_gemm_k(
    const u16* __restrict__ xin, const float* __restrict__ xfin,
    const float* __restrict__ lng, const float* __restrict__ lnb,
    const u16* __restrict__ wqkvt,
    const float* __restrict__ bq, const float* __restrict__ bk,
    const float* __restrict__ bv,
    u16* __restrict__ qo, u16* __restrict__ ko, u16* __restrict__ vto) {
  __shared__ __align__(16) u16 xs[64][136];
  __shared__ __align__(16) u16 wt[64][136];
  const int tid = threadIdx.x;
  const int w = tid >> 6, lane = tid & 63;
  const int lo = lane & 15, hi = lane >> 4, hi4 = hi * 4;
  const int m0 = blockIdx.x * 64;
  const int widx = blockIdx.y >> 1;
  const int n0 = (blockIdx.y & 1) * 64;
  {
    const int r = tid >> 2, sg = tid & 3;
    if (PATH == 0) {
      const u16* sx = &xin[(size_t)(m0 + r) * CC + sg * 32];
#pragma unroll
      for (int j = 0; j < 4; ++j)
        *reinterpret_cast<u16x8*>(&xs[r][sg * 32 + j * 8]) = *reinterpret_cast<const u16x8*>(&sx[j * 8]);
    } else {
      // fused LayerNorm staging: thread holds 32 fp32 of row (m0+r)
      const float* sx = &xfin[(size_t)(m0 + r) * CC + sg * 32];
      float vb[32];
      float s = 0.f, sq = 0.f;
#pragma unroll
      for (int j = 0; j < 32; j += 4) {
        const float4 f = *reinterpret_cast<const float4*>(&sx[j]);
        vb[j] = f.x; vb[j + 1] = f.y; vb[j + 2] = f.z; vb[j + 3] = f.w;
        s += (f.x + f.y) + (f.z + f.w);
        sq += (f.x * f.x + f.y * f.y) + (f.z * f.z + f.w * f.w);
      }
      s += __shfl_xor(s, 1);  s += __shfl_xor(s, 2);
      sq += __shfl_xor(sq, 1); sq += __shfl_xor(sq, 2);
      const float mu = s * 0.0078125f;
      const float rsig = rsqrtf(sq * 0.0078125f - mu * mu + 1e-5f);
#pragma unroll
      for (int j = 0; j < 32; j += 2) {
        const int c = sg * 32 + j;
        const float a = (vb[j] - mu) * rsig * lng[c] + lnb[c];
        const float b_ = (vb[j + 1] - mu) * rsig * lng[c + 1] + lnb[c + 1];
        *reinterpret_cast<unsigned*>(&xs[r][c]) = pk2bf(a, b_);
      }
    }
    const u16* sw = &wqkvt[(size_t)widx * CC * CC + (size_t)(n0 + r) * CC + sg * 32];
#pragma unroll
    for (int j = 0; j < 4; ++j)
      *reinterpret_cast<u16x8*>(&wt[r][sg * 32 + j * 8]) = *reinterpret_cast<const u16x8*>(&sw[j * 8]);
  }
  __syncthreads();
  if (widx < 2) {
    const float* bias = (widx == 0) ? bq : bk;
    u16* outp = (widx == 0) ? qo : ko;
    const float oscale = (widx == 0) ? SCALE_L2E : 1.0f;
    f32x4 acc[4];
#pragma unroll
    for (int st = 0; st < 4; ++st) {
      const float b_ = bias[n0 + st * 16 + lo];
      acc[st] = (f32x4){b_, b_, b_, b_};
    }
#pragma unroll
    for (int kk = 0; kk < 4; ++kk) {
      const bf16x8 af = *reinterpret_cast<const bf16x8*>(&xs[w * 16 + lo][kk * 32 + 8 * hi]);
#pragma unroll
      for (int st = 0; st < 4; ++st) {
        const bf16x8 bfr = *reinterpret_cast<const bf16x8*>(&wt[st * 16 + lo][kk * 32 + 8 * hi]);
        acc[st] = __builtin_amdgcn_mfma_f32_16x16x32_bf16(af, bfr, acc[st], 0, 0, 0);
      }
    }
#pragma unroll
    for (int r = 0; r < 4; ++r) {
      const int mm = m0 + w * 16 + hi4 + r;
      size_t rowbase, hstride;
      if (PATH == 0) {
        const int win = mm / 49, tok = mm - win * 49;
        rowbase = ((size_t)(win * 4) * 49 + tok) * DK;
        hstride = (size_t)49 * DK;
      } else {
        const int b = mm / S_GLB, s = mm - b * S_GLB;
        rowbase = ((size_t)(b * 4) * S_GLB + s) * DK;
        hstride = (size_t)S_GLB * DK;
      }
#pragma unroll
      for (int st = 0; st < 4; ++st) {
        const int c = n0 + st * 16 + lo, h = c >> 5, d = c & 31;
        outp[rowbase + (size_t)h * hstride + d] = f2bf(acc[st][r] * oscale);
      }
    }
  } else {
    f32x4 bias4;
#pragma unroll
    for (int r = 0; r < 4; ++r) bias4[r] = bv[n0 + w * 16 + hi4 + r];
    f32x4 acc[4];
#pragma unroll
    for (int st = 0; st < 4; ++st) acc[st] = bias4;
#pragma unroll
    for (int kk = 0; kk < 4; ++kk) {
      const bf16x8 af = *reinterpret_cast<const bf16x8*>(&wt[w * 16 + lo][kk * 32 + 8 * hi]);
#pragma unroll
      for (int st = 0; st < 4; ++st) {
        const bf16x8 bfr = *reinterpret_cast<const bf16x8*>(&xs[st * 16 + lo][kk * 32 + 8 * hi]);
        acc[st] = __builtin_amdgcn_mfma_f32_16x16x32_bf16(af, bfr, acc[st], 0, 0, 0);
      }
    }
#pragma unroll
    for (int st = 0; st < 4; ++st) {
      const int mm = m0 + st * 16 + lo;
#pragma unroll
      for (int r = 0; r < 4; ++r) {
        const int c = n0 + w * 16 + hi4 + r;
        if (PATH == 0) {
          vto[(size_t)c * VTW_STRIDE + mm] = f2bf(acc[st][r]);
        } else {
          const int b = mm / S_GLB, s = mm - b * S_GLB;
          vto[((size_t)b * CC + c) * S_GLB + s] = f2bf(acc[st][r]);
        }
      }
    }
  }
}

// ---------------- window attention: no-max exp2 softmax, l via ones-MFMA
__global__ __launch_bounds__(256) void win_attn_k(
    const u16* __restrict__ qw, const u16* __restrict__ kw,
    const u16* __restrict__ vtw, u16* __restrict__ aow) {
  __shared__ __align__(16) u16 psh[4][16][72];
  const int tid = threadIdx.x;
  const int wvi = tid >> 6, lane = tid & 63;
  const int lo = lane & 15, hi = lane >> 4, hi4 = hi * 4;
  const int wh = blockIdx.x * 4 + wvi;
  const int win = wh >> 2, hd = wh & 3;
  const f32x4 zero4 = {0.f, 0.f, 0.f, 0.f};
  bf16x8 ones;
#pragma unroll
  for (int j = 0; j < 8; ++j) ones[j] = (short)0x3F80;

  bf16x8 kf[4], vf[2][2];
#pragma unroll
  for (int st = 0; st < 4; ++st)
    kf[st] = *reinterpret_cast<const bf16x8*>(&kw[((size_t)wh * 49 + st * 16 + lo) * DK + 8 * hi]);
#pragma unroll
  for (int dst = 0; dst < 2; ++dst)
#pragma unroll
    for (int kch = 0; kch < 2; ++kch)
      vf[dst][kch] = *reinterpret_cast<const bf16x8*>(
          &vtw[(size_t)(hd * DK + dst * 16 + lo) * VTW_STRIDE + win * 49 + kch * 32 + 8 * hi]);

#pragma unroll
  for (int g = 0; g < 4; ++g) {
    const bf16x8 qf = *reinterpret_cast<const bf16x8*>(
        &qw[((size_t)wh * 49 + g * 16 + lo) * DK + 8 * hi]);
    f32x4 s4[4];
#pragma unroll
    for (int st = 0; st < 4; ++st) {
      s4[st] = __builtin_amdgcn_mfma_f32_16x16x32_bf16(kf[st], qf, zero4, 0, 0, 0);
#pragma unroll
      for (int r = 0; r < 4; ++r)
        if (st * 16 + hi4 + r >= 49) s4[st][r] = -1e30f;  // mask pad keys -> p=0
    }
#pragma unroll
    for (int st = 0; st < 4; ++st) {
      uint2 pk;
      pk.x = pk2bf(fexp2(s4[st][0]), fexp2(s4[st][1]));
      pk.y = pk2bf(fexp2(s4[st][2]), fexp2(s4[st][3]));
      *reinterpret_cast<uint2*>(&psh[wvi][lo][st * 16 + hi4]) = pk;
    }
    asm volatile("" ::: "memory");
    f32x4 acc0 = zero4, acc1 = zero4, lacc = zero4;
#pragma unroll
    for (int kch = 0; kch < 2; ++kch) {
      const bf16x8 pa = *reinterpret_cast<const bf16x8*>(&psh[wvi][lo][kch * 32 + 8 * hi]);
      acc0 = __builtin_amdgcn_mfma_f32_16x16x32_bf16(pa, vf[0][kch], acc0, 0, 0, 0);
      acc1 = __builtin_amdgcn_mfma_f32_16x16x32_bf16(pa, vf[1][kch], acc1, 0, 0, 0);
      lacc = __builtin_amdgcn_mfma_f32_16x16x32_bf16(pa, ones, lacc, 0, 0, 0);
    }
#pragma unroll
    for (int r = 0; r < 4; ++r) {
      const int qrow = g * 16 + hi4 + r;
      if (qrow < 49) {
        const float rl = 1.0f / lacc[r];
        const size_t tw = (size_t)win * 49 + qrow;
        aow[tw * CC + hd * DK + lo] = f2bf(acc0[r] * rl);
        aow[tw * CC + hd * DK + 16 + lo] = f2bf(acc1[r] * rl);
      }
    }
  }
}

// ---------------- global attention v3: global_load_lds 2-phase, swizzled V/P
__global__ __launch_bounds__(256) void glb_attn_k(
    const u16* __restrict__ qg, const u16* __restrict__ kg,
    const u16* __restrict__ vtg, u16* __restrict__ aog) {
  __shared__ __align__(16) u16 ksh[2][64][32];   // linear, conflict-free reads
  __shared__ __align__(16) u16 vtsh[2][32][64];  // content XOR-swizzled via source
  __shared__ __align__(16) u16 psh[4][16][64];   // XOR-swizzled write/read
  const int tid = threadIdx.x;
  const int w = tid >> 6, lane = tid & 63;
  const int lo = lane & 15, hi = lane >> 4, hi4 = hi * 4;
  const int bh = blockIdx.y;
  const int q0 = blockIdx.x * 64;
  const f32x4 zero4 = {0.f, 0.f, 0.f, 0.f};
  bf16x8 ones;
#pragma unroll
  for (int j = 0; j < 8; ++j) ones[j] = (short)0x3F80;

  const bf16x8 qfrag = *reinterpret_cast<const bf16x8*>(
      &qg[((size_t)bh * S_GLB + q0 + w * 16 + lo) * DK + 8 * hi]);
  const u16* kg0 = kg + (size_t)bh * S_GLB * DK;
  const u16* vg0 = vtg + (size_t)bh * DK * S_GLB;

  // per-lane staging sources. K: wave w stages rows [w*16, w*16+16), linear.
  // V: wave w stages rows [w*8, w*8+8); source chunk pre-swizzled so LDS
  // linear dest receives XOR-swizzled content (rule: swizzle src, not dest).
  const u16* ksrc = kg0 + (size_t)(w * 16 + (lane >> 2)) * DK + (lane & 3) * 8;
  const u16* vsrc = vg0 + (size_t)(w * 8 + (lane >> 3)) * S_GLB + ((lane & 7) ^ (lane >> 3)) * 8;
  u16* kdst0 = &ksh[0][w * 16][0]; u16* kdst1 = &ksh[1][w * 16][0];
  u16* vdst0 = &vtsh[0][w * 8][0]; u16* vdst1 = &vtsh[1][w * 8][0];

  f32x4 oacc0 = zero4, oacc1 = zero4, lacc = zero4;

  gload16(ksrc, kdst0);
  gload16(vsrc, vdst0);
  __syncthreads();

  char* const pbase = (char*)&psh[w][lo][0];
  char* const vbase0 = (char*)&vtsh[0][0][0];
  const unsigned swz = (unsigned)(lo & 7) << 4;

  for (int kt = 0; kt < 49; ++kt) {
    const int cur = kt & 1;
    if (kt + 1 < 49) {  // issue next-tile DMA before compute (2-phase)
      gload16(ksrc + (size_t)(kt + 1) * 64 * DK, cur ? kdst0 : kdst1);
      gload16(vsrc + (size_t)(kt + 1) * 64, cur ? vdst0 : vdst1);
    }
    // S^T = K * Q^T
    f32x4 s4[4];
#pragma unroll
    for (int st = 0; st < 4; ++st) {
      const bf16x8 kfrag = *reinterpret_cast<const bf16x8*>(&ksh[cur][st * 16 + lo][8 * hi]);
      s4[st] = __builtin_amdgcn_mfma_f32_16x16x32_bf16(kfrag, qfrag, zero4, 0, 0, 0);
    }
    // p = exp2(s), pack to bf16, swizzled P store
#pragma unroll
    for (int st = 0; st < 4; ++st) {
      uint2 pk;
      pk.x = pk2bf(fexp2(s4[st][0]), fexp2(s4[st][1]));
      pk.y = pk2bf(fexp2(s4[st][2]), fexp2(s4[st][3]));
      *reinterpret_cast<uint2*>(pbase + (((unsigned)(st * 32 + hi * 8)) ^ swz)) = pk;
    }
    asm volatile("" ::: "memory");
    // PV + l via ones-MFMA
    char* const vrow0 = vbase0 + (size_t)cur * (32 * 64 * 2) + lo * 128;
#pragma unroll
    for (int kch = 0; kch < 2; ++kch) {
      const unsigned off = ((unsigned)(kch * 64 + hi * 16)) ^ swz;
      const bf16x8 pa = *reinterpret_cast<const bf16x8*>(pbase + off);
      const bf16x8 v0 = *reinterpret_cast<const bf16x8*>(vrow0 + off);
      const bf16x8 v1 = *reinterpret_cast<const bf16x8*>(vrow0 + 16 * 128 + off);
      oacc0 = __builtin_amdgcn_mfma_f32_16x16x32_bf16(pa, v0, oacc0, 0, 0, 0);
      oacc1 = __builtin_amdgcn_mfma_f32_16x16x32_bf16(pa, v1, oacc1, 0, 0, 0);
      lacc = __builtin_amdgcn_mfma_f32_16x16x32_bf16(pa, ones, lacc, 0, 0, 0);
    }
    __syncthreads();  // drains vmcnt: next tile landed; cur free to overwrite
  }

  const int b = bh >> 2, hd = bh & 3;
#pragma unroll
  for (int r = 0; r < 4; ++r) {
    const float rl = 1.0f / lacc[r];
    const size_t t = (size_t)b * S_GLB + q0 + w * 16 + hi4 + r;
    aog[t * CC + hd * DK + lo] = f2bf(oacc0[r] * rl);
    aog[t * CC + hd * DK + 16 + lo] = f2bf(oacc1[r] * rl);
  }
}

// ---------------- output projection GEMM. MODE 0: window-reverse scatter,
// MODE 1: identity rows + residual.
template <int MODE>
__global__ __launch_bounds__(256) void proj_gemm_k(
    const u16* __restrict__ ain, const u16* __restrict__ wot,
    const float* __restrict__ bo, const float* __restrict__ resid,
    float* __restrict__ xfo) {
  __shared__ __align__(16) u16 xs[64][136];
  __shared__ __align__(16) u16 wt[64][136];
  const int tid = threadIdx.x;
  const int w = tid >> 6, lane = tid & 63;
  const int lo = lane & 15, hi = lane >> 4, hi4 = hi * 4;
  const int m0 = blockIdx.x * 64;
  const int n0 = blockIdx.y * 64;
  {
    const int r = tid >> 2, sg = tid & 3;
    const u16* sx = &ain[(size_t)(m0 + r) * CC + sg * 32];
    const u16* sw = &wot[(size_t)(n0 + r) * CC + sg * 32];
#pragma unroll
    for (int j = 0; j < 4; ++j) {
      *reinterpret_cast<u16x8*>(&xs[r][sg * 32 + j * 8]) = *reinterpret_cast<const u16x8*>(&sx[j * 8]);
      *reinterpret_cast<u16x8*>(&wt[r][sg * 32 + j * 8]) = *reinterpret_cast<const u16x8*>(&sw[j * 8]);
    }
  }
  __syncthreads();
  f32x4 acc[4];
#pragma unroll
  for (int st = 0; st < 4; ++st) {
    const float b_ = bo[n0 + st * 16 + lo];
    acc[st] = (f32x4){b_, b_, b_, b_};
  }
#pragma unroll
  for (int kk = 0; kk < 4; ++kk) {
    const bf16x8 af = *reinterpret_cast<const bf16x8*>(&xs[w * 16 + lo][kk * 32 + 8 * hi]);
#pragma unroll
    for (int st = 0; st < 4; ++st) {
      const bf16x8 bfr = *reinterpret_cast<const bf16x8*>(&wt[st * 16 + lo][kk * 32 + 8 * hi]);
      acc[st] = __builtin_amdgcn_mfma_f32_16x16x32_bf16(af, bfr, acc[st], 0, 0, 0);
    }
  }
#pragma unroll
  for (int r = 0; r < 4; ++r) {
    const int mm = m0 + w * 16 + hi4 + r;
    size_t trow;
    if (MODE == 0) {
      const int win = mm / 49, tok = mm - win * 49;
      const int b = win >> 6, wi = (win >> 3) & 7, wj = win & 7;
      const int ii = tok / 7, jj = tok - ii * 7;
      int hr = wi * 7 + ii + SHIFT; if (hr >= HW) hr -= HW;
      int wr = wj * 7 + jj + SHIFT; if (wr >= HW) wr -= HW;
      trow = ((size_t)b * S_GLB + hr * HW + wr) * CC;
    } else {
      trow = (size_t)mm * CC;
    }
#pragma unroll
    for (int st = 0; st < 4; ++st) {
      const int c = n0 + st * 16 + lo;
      if (MODE == 1)
        xfo[trow + c] = resid[trow + c] + acc[st][r];
      else
        xfo[trow + c] = acc[st][r];
    }
  }
}

// ---------------- GEMM1 [NTOK,128]@[128,512] with fused LN2 staging + gelu
__global__ __launch_bounds__(256) void gemm1_k(
    const float* __restrict__ xfin, const float* __restrict__ lng,
    const float* __restrict__ lnb, const u16* __restrict__ w1t,
    const float* __restrict__ b1, u16* __restrict__ hb) {
  __shared__ __align__(16) u16 xs[64][136];
  __shared__ __align__(16) u16 wt[64][136];
  const int tid = threadIdx.x;
  const int w = tid >> 6, lane = tid & 63;
  const int lo = lane & 15, hi = lane >> 4;
  const int m0 = blockIdx.x * 64, n0 = blockIdx.y * 64;
  {
    const int r = tid >> 2, sg = tid & 3;
    const float* sx = &xfin[(size_t)(m0 + r) * CC + sg * 32];
    float vb[32];
    float s = 0.f, sq = 0.f;
#pragma unroll
    for (int j = 0; j < 32; j += 4) {
      const float4 f = *reinterpret_cast<const float4*>(&sx[j]);
      vb[j] = f.x; vb[j + 1] = f.y; vb[j + 2] = f.z; vb[j + 3] = f.w;
      s += (f.x + f.y) + (f.z + f.w);
      sq += (f.x * f.x + f.y * f.y) + (f.z * f.z + f.w * f.w);
    }
    s += __shfl_xor(s, 1);  s += __shfl_xor(s, 2);
    sq += __shfl_xor(sq, 1); sq += __shfl_xor(sq, 2);
    const float mu = s * 0.0078125f;
    const float rsig = rsqrtf(sq * 0.0078125f - mu * mu + 1e-5f);
#pragma unroll
    for (int j = 0; j < 32; j += 2) {
      const int c = sg * 32 + j;
      const float a = (vb[j] - mu) * rsig * lng[c] + lnb[c];
      const float b_ = (vb[j + 1] - mu) * rsig * lng[c + 1] + lnb[c + 1];
      *reinterpret_cast<unsigned*>(&xs[r][c]) = pk2bf(a, b_);
    }
    const u16* src_w = &w1t[(size_t)(n0 + r) * CC + sg * 32];
#pragma unroll
    for (int j = 0; j < 4; ++j)
      *reinterpret_cast<u16x8*>(&wt[r][sg * 32 + j * 8]) = *reinterpret_cast<const u16x8*>(&src_w[j * 8]);
  }
  __syncthreads();
  f32x4 acc[4];
#pragma unroll
  for (int st = 0; st < 4; ++st) {
    const float bv = b1[n0 + st * 16 + lo];
    acc[st] = (f32x4){bv, bv, bv, bv};
  }
#pragma unroll
  for (int kk = 0; kk < 4; ++kk) {
    const bf16x8 af = *reinterpret_cast<const bf16x8*>(&xs[w * 16 + lo][kk * 32 + 8 * hi]);
#pragma unroll
    for (int st = 0; st < 4; ++st) {
      const bf16x8 bfr = *reinterpret_cast<const bf16x8*>(&wt[st * 16 + lo][kk * 32 + 8 * hi]);
      acc[st] = __builtin_amdgcn_mfma_f32_16x16x32_bf16(af, bfr, acc[st], 0, 0, 0);
    }
  }
#pragma unroll
  for (int st = 0; st < 4; ++st) {
#pragma unroll
    for (int r = 0; r < 4; ++r) {
      const float val = acc[st][r];
      const float gel = 0.5f * val * (1.0f + erff(val * 0.70710678118f));
      hb[(size_t)(m0 + w * 16 + (hi << 2) + r) * 512 + n0 + st * 16 + lo] = f2bf(gel);
    }
  }
}

// ---------------- GEMM2 [NTOK,512]@[512,128] + residual -> out
__global__ __launch_bounds__(256) void gemm2_k(
    const u16* __restrict__ hb, const u16* __restrict__ w2t,
    const float* __restrict__ b2, const float* __restrict__ xf,
    float* __restrict__ out) {
  __shared__ __align__(16) u16 xs[64][136];
  __shared__ __align__(16) u16 wt[64][136];
  const int tid = threadIdx.x;
  const int w = tid >> 6, lane = tid & 63;
  const int lo = lane & 15, hi = lane >> 4;
  const int m0 = blockIdx.x * 64, n0 = blockIdx.y * 64;
  f32x4 acc[4];
#pragma unroll
  for (int st = 0; st < 4; ++st) {
    const float bv = b2[n0 + st * 16 + lo];
    acc[st] = (f32x4){bv, bv, bv, bv};
  }
  for (int kc = 0; kc < 4; ++kc) {
    if (kc) __syncthreads();
    {
      const int r = tid >> 2, sg = tid & 3;
      const u16* src_x = &hb[(size_t)(m0 + r) * 512 + kc * 128 + sg * 32];
      const u16* src_w = &w2t[(size_t)(n0 + r) * 512 + kc * 128 + sg * 32];
#pragma unroll
      for (int j = 0; j < 4; ++j) {
        *reinterpret_cast<u16x8*>(&xs[r][sg * 32 + j * 8]) = *reinterpret_cast<const u16x8*>(&src_x[j * 8]);
        *reinterpret_cast<u16x8*>(&wt[r][sg * 32 + j * 8]) = *reinterpret_cast<const u16x8*>(&src_w[j * 8]);
      }
    }
    __syncthreads();
#pragma unroll
    for (int kk = 0; kk < 4; ++kk) {
      const bf16x8 af = *reinterpret_cast<const bf16x8*>(&xs[w * 16 + lo][kk * 32 + 8 * hi]);
#pragma unroll
      for (int st = 0; st < 4; ++st) {
        const bf16x8 bfr = *reinterpret_cast<const bf16x8*>(&wt[st * 16 + lo][kk * 32 + 8 * hi]);
        acc[st] = __builtin_amdgcn_mfma_f32_16x16x32_bf16(af, bfr, acc[st], 0, 0, 0);
      }
    }
  }
#pragma unroll
  for (int st = 0; st < 4; ++st) {
#pragma unroll
    for (int r = 0; r < 4; ++r) {
      const size_t idx = (size_t)(m0 + w * 16 + (hi << 2) + r) * CC + n0 + st * 16 + lo;
      out[idx] = xf[idx] + acc[st][r];
    }
  }
}

extern "C" void kernel_launch(void* const* d_in, const int* in_sizes, int n_in,
                              void* d_out, int out_size, void* d_ws, size_t ws_size,
                              hipStream_t stream) {
  (void)in_sizes; (void)n_in; (void)out_size; (void)ws_size;
  const float* x   = (const float*)d_in[0];
  const float* wq  = (const float*)d_in[1];
  const float* bq  = (const float*)d_in[2];
  const float* wk  = (const float*)d_in[3];
  const float* bk  = (const float*)d_in[4];
  const float* wv  = (const float*)d_in[5];
  const float* bv  = (const float*)d_in[6];
  const float* wo  = (const float*)d_in[7];
  const float* bo  = (const float*)d_in[8];
  const float* w1  = (const float*)d_in[9];
  const float* b1  = (const float*)d_in[10];
  const float* w2  = (const float*)d_in[11];
  const float* b2  = (const float*)d_in[12];
  const float* g1  = (const float*)d_in[13];
  const float* be1 = (const float*)d_in[14];
  const float* g2  = (const float*)d_in[15];
  const float* be2 = (const float*)d_in[16];
  float* out = (float*)d_out;

  char* p = (char*)d_ws;
  auto alloc = [&](size_t bytes) { char* r = p; p += (bytes + 255) & ~(size_t)255; return r; };
  float* xf  = (float*)alloc((size_t)NTOK * CC * 4);
  u16* xg    = (u16*)alloc((size_t)NTOK * CC * 2);
  u16* qw    = (u16*)alloc((size_t)NTOK * CC * 2 + 4096);
  u16* kw    = (u16*)alloc((size_t)NTOK * CC * 2 + 4096);
  u16* vtw   = (u16*)alloc((size_t)CC * VTW_STRIDE * 2);
  u16* aow   = (u16*)alloc((size_t)NTOK * CC * 2);
  u16* hb    = (u16*)alloc((size_t)NTOK * 512 * 2);
  u16* wqkvt = (u16*)alloc(3 * 16384 * 2);
  u16* wot   = (u16*)alloc(16384 * 2);
  u16* w1t   = (u16*)alloc(65536 * 2);
  u16* w2t   = (u16*)alloc(65536 * 2);

  cvt_all_k<<<768, 256, 0, stream>>>(w1, w2, wq, wk, wv, wo, w1t, w2t, wqkvt, wot);

  win_gather_k<<<NTOK / 2, 256, 0, stream>>>(x, xg);
  qkv_gemm_k<0><<<dim3(NTOK / 64, 6), 256, 0, stream>>>(
      xg, nullptr, nullptr, nullptr, wqkvt, bq, bk, bv, qw, kw, vtw);
  win_attn_k<<<256, 256, 0, stream>>>(qw, kw, vtw, aow);
  proj_gemm_k<0><<<dim3(NTOK / 64, 2), 256, 0, stream>>>(aow, wot, bo, nullptr, xf);

  qkv_gemm_k<1><<<dim3(NTOK / 64, 6), 256, 0, stream>>>(
      nullptr, xf, g1, be1, wqkvt, bq, bk, bv, qw, kw, vtw);
  glb_attn_k<<<dim3(S_GLB / 64, 16), 256, 0, stream>>>(qw, kw, vtw, aow);
  proj_gemm_k<1><<<dim3(NTOK / 64, 2), 256, 0, stream>>>(aow, wot, bo, xf, xf);

  gemm1_k<<<dim3(NTOK / 64, 8), 256, 0, stream>>>(xf, g2, be2, w1t, b1, hb);
  gemm2_k<<<dim3(NTOK / 64, 2), 256, 0, stream>>>(hb, w2t, b2, xf, out);
}

// Round 7
// 123.295 us; speedup vs baseline: 1.1320x; 1.1320x over previous
//
#include <hip/hip_runtime.h>
#include <hip/hip_bf16.h>
#include <math.h>

#define NH 4
#define DK 32
#define CC 128
#define HW 56
#define SHIFT 3
#define NTOK 12544   // 4*56*56 == 256*49
#define S_GLB 3136
#define VTW_STRIDE 12608
#define SCALE_L2E 0.25503488f  // log2(e)/sqrt(32): exp2-domain softmax scale

typedef unsigned short u16;
typedef short bf16x8 __attribute__((ext_vector_type(8)));
typedef unsigned short u16x8 __attribute__((ext_vector_type(8)));
typedef float f32x4 __attribute__((ext_vector_type(4)));

static __device__ __forceinline__ u16 f2bf(float f) {
  unsigned int b = __builtin_bit_cast(unsigned int, f);
  return (u16)((b + 0x7FFFu + ((b >> 16) & 1u)) >> 16);
}
static __device__ __forceinline__ unsigned pk2bf(float a, float b) {
  unsigned r;
  asm("v_cvt_pk_bf16_f32 %0, %1, %2" : "=v"(r) : "v"(a), "v"(b));
  return r;
}
static __device__ __forceinline__ float fexp2(float x) {
  float r;
  asm("v_exp_f32 %0, %1" : "=v"(r) : "v"(x));
  return r;
}
static __device__ __forceinline__ void gload16(const void* g, void* l) {
  __builtin_amdgcn_global_load_lds(
      (const __attribute__((address_space(1))) unsigned int*)g,
      (__attribute__((address_space(3))) unsigned int*)l, 16, 0, 0);
}

// ---------------- all weight converts in one kernel
__global__ __launch_bounds__(256) void cvt_all_k(
    const float* __restrict__ w1, const float* __restrict__ w2,
    const float* __restrict__ wq, const float* __restrict__ wk,
    const float* __restrict__ wv, const float* __restrict__ wo,
    u16* __restrict__ w1t, u16* __restrict__ w2t,
    u16* __restrict__ wqkvt, u16* __restrict__ wot) {
  const int idx = blockIdx.x * 256 + threadIdx.x;
  if (idx < 65536) {            // w1 [128][512] -> w1t [512][128]
    const int c = idx >> 7, r = idx & 127;
    w1t[idx] = f2bf(w1[r * 512 + c]);
  } else if (idx < 131072) {    // w2 [512][128] -> w2t [128][512]
    const int o = idx - 65536;
    const int c = o / 512, r = o - c * 512;
    w2t[o] = f2bf(w2[r * 128 + c]);
  } else {                      // four 128x128 -> transposed
    const int o = idx - 131072;
    const int which = o >> 14, oo = o & 16383;
    const int c = oo >> 7, r = oo & 127;
    const float* src = (which == 0) ? wq : (which == 1) ? wk : (which == 2) ? wv : wo;
    u16* dst = (which < 3) ? (wqkvt + which * 16384) : wot;
    dst[oo] = f2bf(src[r * 128 + c]);
  }
}

// ---------------- shift + window-partition gather -> bf16 [t_w][128]
__global__ __launch_bounds__(256) void win_gather_k(
    const float* __restrict__ x, u16* __restrict__ xg) {
  const int t = blockIdx.x * 2 + (threadIdx.x >> 7);
  const int c = threadIdx.x & 127;
  const int win = t / 49, tok = t % 49;
  const int b = win >> 6, wrem = win & 63;
  const int wi = wrem >> 3, wj = wrem & 7;
  const int i = tok / 7, j = tok % 7;
  int hh = wi * 7 + i + SHIFT; if (hh >= HW) hh -= HW;
  int ww = wj * 7 + j + SHIFT; if (ww >= HW) ww -= HW;
  xg[(size_t)t * CC + c] = f2bf(x[((size_t)(b * HW + hh) * HW + ww) * CC + c]);
}

// ---------------- LayerNorm fp32 -> bf16
__global__ __launch_bounds__(128) void ln_k(
    const float* __restrict__ xf, const float* __restrict__ g,
    const float* __restrict__ be, u16* __restrict__ ybf) {
  __shared__ float xs[8][CC];
  __shared__ float red[8][2];
  const int t0 = blockIdx.x * 8;
  const int tid = threadIdx.x;
  for (int t2 = 0; t2 < 8; ++t2) xs[t2][tid] = xf[(size_t)(t0 + t2) * CC + tid];
  __syncthreads();
  const int wvi = tid >> 6, lane = tid & 63;
  for (int t2 = wvi * 4; t2 < wvi * 4 + 4; ++t2) {
    const float v0 = xs[t2][lane], v1 = xs[t2][64 + lane];
    float s = v0 + v1, sq = v0 * v0 + v1 * v1;
#pragma unroll
    for (int off = 1; off < 64; off <<= 1) { s += __shfl_xor(s, off); sq += __shfl_xor(sq, off); }
    if (lane == 0) {
      const float mu = s * 0.0078125f;
      const float var = sq * 0.0078125f - mu * mu;
      red[t2][0] = mu; red[t2][1] = rsqrtf(var + 1e-5f);
    }
  }
  __syncthreads();
  const float gg = g[tid], bb = be[tid];
  for (int t2 = 0; t2 < 8; ++t2)
    ybf[(size_t)(t0 + t2) * CC + tid] = f2bf((xs[t2][tid] - red[t2][0]) * red[t2][1] * gg + bb);
}

// ---------------- fused QKV GEMM. PATH 0: window layout, PATH 1: global layout.
template <int PATH>
__global__ __launch_bounds__(256) void qkv_gemm_k(
    const u16* __restrict__ xin, const u16* __restrict__ wqkvt,
    const float* __restrict__ bq, const float* __restrict__ bk,
    const float* __restrict__ bv,
    u16* __restrict__ qo, u16* __restrict__ ko, u16* __restrict__ vto) {
  __shared__ __align__(16) u16 xs[64][136];
  __shared__ __align__(16) u16 wt[64][136];
  const int tid = threadIdx.x;
  const int w = tid >> 6, lane = tid & 63;
  const int lo = lane & 15, hi = lane >> 4, hi4 = hi * 4;
  const int m0 = blockIdx.x * 64;
  const int widx = blockIdx.y >> 1;
  const int n0 = (blockIdx.y & 1) * 64;
  {
    const int r = tid >> 2, sg = tid & 3;
    const u16* sx = &xin[(size_t)(m0 + r) * CC + sg * 32];
    const u16* sw = &wqkvt[(size_t)widx * CC * CC + (size_t)(n0 + r) * CC + sg * 32];
#pragma unroll
    for (int j = 0; j < 4; ++j) {
      *reinterpret_cast<u16x8*>(&xs[r][sg * 32 + j * 8]) = *reinterpret_cast<const u16x8*>(&sx[j * 8]);
      *reinterpret_cast<u16x8*>(&wt[r][sg * 32 + j * 8]) = *reinterpret_cast<const u16x8*>(&sw[j * 8]);
    }
  }
  __syncthreads();
  if (widx < 2) {
    const float* bias = (widx == 0) ? bq : bk;
    u16* outp = (widx == 0) ? qo : ko;
    const float oscale = (widx == 0) ? SCALE_L2E : 1.0f;
    f32x4 acc[4];
#pragma unroll
    for (int st = 0; st < 4; ++st) {
      const float b_ = bias[n0 + st * 16 + lo];
      acc[st] = (f32x4){b_, b_, b_, b_};
    }
#pragma unroll
    for (int kk = 0; kk < 4; ++kk) {
      const bf16x8 af = *reinterpret_cast<const bf16x8*>(&xs[w * 16 + lo][kk * 32 + 8 * hi]);
#pragma unroll
      for (int st = 0; st < 4; ++st) {
        const bf16x8 bfr = *reinterpret_cast<const bf16x8*>(&wt[st * 16 + lo][kk * 32 + 8 * hi]);
        acc[st] = __builtin_amdgcn_mfma_f32_16x16x32_bf16(af, bfr, acc[st], 0, 0, 0);
      }
    }
#pragma unroll
    for (int r = 0; r < 4; ++r) {
      const int mm = m0 + w * 16 + hi4 + r;
      size_t rowbase, hstride;
      if (PATH == 0) {
        const int win = mm / 49, tok = mm - win * 49;
        rowbase = ((size_t)(win * 4) * 49 + tok) * DK;
        hstride = (size_t)49 * DK;
      } else {
        const int b = mm / S_GLB, s = mm - b * S_GLB;
        rowbase = ((size_t)(b * 4) * S_GLB + s) * DK;
        hstride = (size_t)S_GLB * DK;
      }
#pragma unroll
      for (int st = 0; st < 4; ++st) {
        const int c = n0 + st * 16 + lo, h = c >> 5, d = c & 31;
        outp[rowbase + (size_t)h * hstride + d] = f2bf(acc[st][r] * oscale);
      }
    }
  } else {
    f32x4 bias4;
#pragma unroll
    for (int r = 0; r < 4; ++r) bias4[r] = bv[n0 + w * 16 + hi4 + r];
    f32x4 acc[4];
#pragma unroll
    for (int st = 0; st < 4; ++st) acc[st] = bias4;
#pragma unroll
    for (int kk = 0; kk < 4; ++kk) {
      const bf16x8 af = *reinterpret_cast<const bf16x8*>(&wt[w * 16 + lo][kk * 32 + 8 * hi]);
#pragma unroll
      for (int st = 0; st < 4; ++st) {
        const bf16x8 bfr = *reinterpret_cast<const bf16x8*>(&xs[st * 16 + lo][kk * 32 + 8 * hi]);
        acc[st] = __builtin_amdgcn_mfma_f32_16x16x32_bf16(af, bfr, acc[st], 0, 0, 0);
      }
    }
#pragma unroll
    for (int st = 0; st < 4; ++st) {
      const int mm = m0 + st * 16 + lo;
#pragma unroll
      for (int r = 0; r < 4; ++r) {
        const int c = n0 + w * 16 + hi4 + r;
        if (PATH == 0) {
          vto[(size_t)c * VTW_STRIDE + mm] = f2bf(acc[st][r]);
        } else {
          const int b = mm / S_GLB, s = mm - b * S_GLB;
          vto[((size_t)b * CC + c) * S_GLB + s] = f2bf(acc[st][r]);
        }
      }
    }
  }
}

// ---------------- window attention: no-max exp2 softmax, l via ones-MFMA
__global__ __launch_bounds__(256) void win_attn_k(
    const u16* __restrict__ qw, const u16* __restrict__ kw,
    const u16* __restrict__ vtw, u16* __restrict__ aow) {
  __shared__ __align__(16) u16 psh[4][16][72];
  const int tid = threadIdx.x;
  const int wvi = tid >> 6, lane = tid & 63;
  const int lo = lane & 15, hi = lane >> 4, hi4 = hi * 4;
  const int wh = blockIdx.x * 4 + wvi;
  const int win = wh >> 2, hd = wh & 3;
  const f32x4 zero4 = {0.f, 0.f, 0.f, 0.f};
  bf16x8 ones;
#pragma unroll
  for (int j = 0; j < 8; ++j) ones[j] = (short)0x3F80;

  bf16x8 kf[4], vf[2][2];
#pragma unroll
  for (int st = 0; st < 4; ++st)
    kf[st] = *reinterpret_cast<const bf16x8*>(&kw[((size_t)wh * 49 + st * 16 + lo) * DK + 8 * hi]);
#pragma unroll
  for (int dst = 0; dst < 2; ++dst)
#pragma unroll
    for (int kch = 0; kch < 2; ++kch)
      vf[dst][kch] = *reinterpret_cast<const bf16x8*>(
          &vtw[(size_t)(hd * DK + dst * 16 + lo) * VTW_STRIDE + win * 49 + kch * 32 + 8 * hi]);

#pragma unroll
  for (int g = 0; g < 4; ++g) {
    const bf16x8 qf = *reinterpret_cast<const bf16x8*>(
        &qw[((size_t)wh * 49 + g * 16 + lo) * DK + 8 * hi]);
    f32x4 s4[4];
#pragma unroll
    for (int st = 0; st < 4; ++st) {
      s4[st] = __builtin_amdgcn_mfma_f32_16x16x32_bf16(kf[st], qf, zero4, 0, 0, 0);
#pragma unroll
      for (int r = 0; r < 4; ++r)
        if (st * 16 + hi4 + r >= 49) s4[st][r] = -1e30f;  // mask pad keys -> p=0
    }
#pragma unroll
    for (int st = 0; st < 4; ++st) {
      uint2 pk;
      pk.x = pk2bf(fexp2(s4[st][0]), fexp2(s4[st][1]));
      pk.y = pk2bf(fexp2(s4[st][2]), fexp2(s4[st][3]));
      *reinterpret_cast<uint2*>(&psh[wvi][lo][st * 16 + hi4]) = pk;
    }
    asm volatile("" ::: "memory");
    f32x4 acc0 = zero4, acc1 = zero4, lacc = zero4;
#pragma unroll
    for (int kch = 0; kch < 2; ++kch) {
      const bf16x8 pa = *reinterpret_cast<const bf16x8*>(&psh[wvi][lo][kch * 32 + 8 * hi]);
      acc0 = __builtin_amdgcn_mfma_f32_16x16x32_bf16(pa, vf[0][kch], acc0, 0, 0, 0);
      acc1 = __builtin_amdgcn_mfma_f32_16x16x32_bf16(pa, vf[1][kch], acc1, 0, 0, 0);
      lacc = __builtin_amdgcn_mfma_f32_16x16x32_bf16(pa, ones, lacc, 0, 0, 0);
    }
#pragma unroll
    for (int r = 0; r < 4; ++r) {
      const int qrow = g * 16 + hi4 + r;
      if (qrow < 49) {
        const float rl = 1.0f / lacc[r];
        const size_t tw = (size_t)win * 49 + qrow;
        aow[tw * CC + hd * DK + lo] = f2bf(acc0[r] * rl);
        aow[tw * CC + hd * DK + 16 + lo] = f2bf(acc1[r] * rl);
      }
    }
  }
}

// ---------------- global attention v4: split-K (z=2) + gload_lds + swizzles.
// Outputs UNNORMALIZED partial O (f32) and partial l; no-max exp2 softmax is
// associative across key splits, so combine is (Oa+Ob)/(la+lb).
__global__ __launch_bounds__(256) void glb_attn_k(
    const u16* __restrict__ qg, const u16* __restrict__ kg,
    const u16* __restrict__ vtg, float* __restrict__ po, float* __restrict__ pl) {
  __shared__ __align__(16) u16 ksh[2][64][32];   // linear, conflict-free reads
  __shared__ __align__(16) u16 vtsh[2][32][64];  // content XOR-swizzled via source
  __shared__ __align__(16) u16 psh[4][16][64];   // XOR-swizzled write/read
  const int tid = threadIdx.x;
  const int w = tid >> 6, lane = tid & 63;
  const int lo = lane & 15, hi = lane >> 4, hi4 = hi * 4;
  const int bh = blockIdx.y;
  const int q0 = blockIdx.x * 64;
  const int sp = blockIdx.z;
  const int kt_beg = sp * 25;
  const int kt_end = sp ? 49 : 25;
  const f32x4 zero4 = {0.f, 0.f, 0.f, 0.f};
  bf16x8 ones;
#pragma unroll
  for (int j = 0; j < 8; ++j) ones[j] = (short)0x3F80;

  const bf16x8 qfrag = *reinterpret_cast<const bf16x8*>(
      &qg[((size_t)bh * S_GLB + q0 + w * 16 + lo) * DK + 8 * hi]);
  const u16* kg0 = kg + (size_t)bh * S_GLB * DK;
  const u16* vg0 = vtg + (size_t)bh * DK * S_GLB;

  const u16* ksrc = kg0 + (size_t)(w * 16 + (lane >> 2)) * DK + (lane & 3) * 8;
  const u16* vsrc = vg0 + (size_t)(w * 8 + (lane >> 3)) * S_GLB + ((lane & 7) ^ (lane >> 3)) * 8;
  u16* kdst0 = &ksh[0][w * 16][0]; u16* kdst1 = &ksh[1][w * 16][0];
  u16* vdst0 = &vtsh[0][w * 8][0]; u16* vdst1 = &vtsh[1][w * 8][0];

  f32x4 oacc0 = zero4, oacc1 = zero4, lacc = zero4;

  gload16(ksrc + (size_t)kt_beg * 64 * DK, kdst0);
  gload16(vsrc + (size_t)kt_beg * 64, vdst0);
  __syncthreads();

  char* const pbase = (char*)&psh[w][lo][0];
  char* const vbase0 = (char*)&vtsh[0][0][0];
  const unsigned swz = (unsigned)(lo & 7) << 4;

  for (int kt = kt_beg; kt < kt_end; ++kt) {
    const int cur = (kt - kt_beg) & 1;
    if (kt + 1 < kt_end) {  // issue next-tile DMA before compute (2-phase)
      gload16(ksrc + (size_t)(kt + 1) * 64 * DK, cur ? kdst0 : kdst1);
      gload16(vsrc + (size_t)(kt + 1) * 64, cur ? vdst0 : vdst1);
    }
    // S^T = K * Q^T
    f32x4 s4[4];
#pragma unroll
    for (int st = 0; st < 4; ++st) {
      const bf16x8 kfrag = *reinterpret_cast<const bf16x8*>(&ksh[cur][st * 16 + lo][8 * hi]);
      s4[st] = __builtin_amdgcn_mfma_f32_16x16x32_bf16(kfrag, qfrag, zero4, 0, 0, 0);
    }
    // p = exp2(s), pack to bf16, swizzled P store
#pragma unroll
    for (int st = 0; st < 4; ++st) {
      uint2 pk;
      pk.x = pk2bf(fexp2(s4[st][0]), fexp2(s4[st][1]));
      pk.y = pk2bf(fexp2(s4[st][2]), fexp2(s4[st][3]));
      *reinterpret_cast<uint2*>(pbase + (((unsigned)(st * 32 + hi * 8)) ^ swz)) = pk;
    }
    asm volatile("" ::: "memory");
    // PV + l via ones-MFMA
    char* const vrow0 = vbase0 + (size_t)cur * (32 * 64 * 2) + lo * 128;
#pragma unroll
    for (int kch = 0; kch < 2; ++kch) {
      const unsigned off = ((unsigned)(kch * 64 + hi * 16)) ^ swz;
      const bf16x8 pa = *reinterpret_cast<const bf16x8*>(pbase + off);
      const bf16x8 v0 = *reinterpret_cast<const bf16x8*>(vrow0 + off);
      const bf16x8 v1 = *reinterpret_cast<const bf16x8*>(vrow0 + 16 * 128 + off);
      oacc0 = __builtin_amdgcn_mfma_f32_16x16x32_bf16(pa, v0, oacc0, 0, 0, 0);
      oacc1 = __builtin_amdgcn_mfma_f32_16x16x32_bf16(pa, v1, oacc1, 0, 0, 0);
      lacc = __builtin_amdgcn_mfma_f32_16x16x32_bf16(pa, ones, lacc, 0, 0, 0);
    }
    __syncthreads();  // drains vmcnt: next tile landed; cur free to overwrite
  }

  const int b = bh >> 2, hd = bh & 3;
  float* pob = po + (size_t)sp * NTOK * CC;
#pragma unroll
  for (int r = 0; r < 4; ++r) {
    const size_t t = (size_t)b * S_GLB + q0 + w * 16 + hi4 + r;
    pob[t * CC + hd * DK + lo] = oacc0[r];
    pob[t * CC + hd * DK + 16 + lo] = oacc1[r];
    if (lo == 0)
      pl[((size_t)sp * 16 + bh) * S_GLB + q0 + w * 16 + hi4 + r] = lacc[r];
  }
}

// ---------------- combine split-K partials -> bf16 attention out
__global__ __launch_bounds__(256) void combine_k(
    const float* __restrict__ po, const float* __restrict__ pl,
    u16* __restrict__ aog) {
  const int t = blockIdx.x * 2 + (threadIdx.x >> 7);
  const int c = threadIdx.x & 127;
  const int b = t / S_GLB, s = t - b * S_GLB;
  const int bh = b * 4 + (c >> 5);
  const float l = pl[(size_t)bh * S_GLB + s] + pl[((size_t)16 + bh) * S_GLB + s];
  const float v = po[(size_t)t * CC + c] + po[(size_t)NTOK * CC + (size_t)t * CC + c];
  aog[(size_t)t * CC + c] = f2bf(v / l);
}

// ---------------- output projection GEMM. MODE 0: window-reverse scatter,
// MODE 1: identity rows + residual.
template <int MODE>
__global__ __launch_bounds__(256) void proj_gemm_k(
    const u16* __restrict__ ain, const u16* __restrict__ wot,
    const float* __restrict__ bo, const float* __restrict__ resid,
    float* __restrict__ xfo) {
  __shared__ __align__(16) u16 xs[64][136];
  __shared__ __align__(16) u16 wt[64][136];
  const int tid = threadIdx.x;
  const int w = tid >> 6, lane = tid & 63;
  const int lo = lane & 15, hi = lane >> 4, hi4 = hi * 4;
  const int m0 = blockIdx.x * 64;
  const int n0 = blockIdx.y * 64;
  {
    const int r = tid >> 2, sg = tid & 3;
    const u16* sx = &ain[(size_t)(m0 + r) * CC + sg * 32];
    const u16* sw = &wot[(size_t)(n0 + r) * CC + sg * 32];
#pragma unroll
    for (int j = 0; j < 4; ++j) {
      *reinterpret_cast<u16x8*>(&xs[r][sg * 32 + j * 8]) = *reinterpret_cast<const u16x8*>(&sx[j * 8]);
      *reinterpret_cast<u16x8*>(&wt[r][sg * 32 + j * 8]) = *reinterpret_cast<const u16x8*>(&sw[j * 8]);
    }
  }
  __syncthreads();
  f32x4 acc[4];
#pragma unroll
  for (int st = 0; st < 4; ++st) {
    const float b_ = bo[n0 + st * 16 + lo];
    acc[st] = (f32x4){b_, b_, b_, b_};
  }
#pragma unroll
  for (int kk = 0; kk < 4; ++kk) {
    const bf16x8 af = *reinterpret_cast<const bf16x8*>(&xs[w * 16 + lo][kk * 32 + 8 * hi]);
#pragma unroll
    for (int st = 0; st < 4; ++st) {
      const bf16x8 bfr = *reinterpret_cast<const bf16x8*>(&wt[st * 16 + lo][kk * 32 + 8 * hi]);
      acc[st] = __builtin_amdgcn_mfma_f32_16x16x32_bf16(af, bfr, acc[st], 0, 0, 0);
    }
  }
#pragma unroll
  for (int r = 0; r < 4; ++r) {
    const int mm = m0 + w * 16 + hi4 + r;
    size_t trow;
    if (MODE == 0) {
      const int win = mm / 49, tok = mm - win * 49;
      const int b = win >> 6, wi = (win >> 3) & 7, wj = win & 7;
      const int ii = tok / 7, jj = tok - ii * 7;
      int hr = wi * 7 + ii + SHIFT; if (hr >= HW) hr -= HW;
      int wr = wj * 7 + jj + SHIFT; if (wr >= HW) wr -= HW;
      trow = ((size_t)b * S_GLB + hr * HW + wr) * CC;
    } else {
      trow = (size_t)mm * CC;
    }
#pragma unroll
    for (int st = 0; st < 4; ++st) {
      const int c = n0 + st * 16 + lo;
      if (MODE == 1)
        xfo[trow + c] = resid[trow + c] + acc[st][r];
      else
        xfo[trow + c] = acc[st][r];
    }
  }
}

// ---------------- GEMM1 [NTOK,128]@[128,512] + gelu -> bf16
__global__ __launch_bounds__(256) void gemm1_k(
    const u16* __restrict__ ybf, const u16* __restrict__ w1t,
    const float* __restrict__ b1, u16* __restrict__ hb) {
  __shared__ __align__(16) u16 xs[64][136];
  __shared__ __align__(16) u16 wt[64][136];
  const int tid = threadIdx.x;
  const int w = tid >> 6, lane = tid & 63;
  const int lo = lane & 15, hi = lane >> 4;
  const int m0 = blockIdx.x * 64, n0 = blockIdx.y * 64;
  {
    const int r = tid >> 2, sg = tid & 3;
    const u16* src_x = &ybf[(size_t)(m0 + r) * CC + sg * 32];
    const u16* src_w = &w1t[(size_t)(n0 + r) * CC + sg * 32];
#pragma unroll
    for (int j = 0; j < 4; ++j) {
      *reinterpret_cast<u16x8*>(&xs[r][sg * 32 + j * 8]) = *reinterpret_cast<const u16x8*>(&src_x[j * 8]);
      *reinterpret_cast<u16x8*>(&wt[r][sg * 32 + j * 8]) = *reinterpret_cast<const u16x8*>(&src_w[j * 8]);
    }
  }
  __syncthreads();
  f32x4 acc[4];
#pragma unroll
  for (int st = 0; st < 4; ++st) {
    const float bv = b1[n0 + st * 16 + lo];
    acc[st] = (f32x4){bv, bv, bv, bv};
  }
#pragma unroll
  for (int kk = 0; kk < 4; ++kk) {
    const bf16x8 af = *reinterpret_cast<const bf16x8*>(&xs[w * 16 + lo][kk * 32 + 8 * hi]);
#pragma unroll
    for (int st = 0; st < 4; ++st) {
      const bf16x8 bfr = *reinterpret_cast<const bf16x8*>(&wt[st * 16 + lo][kk * 32 + 8 * hi]);
      acc[st] = __builtin_amdgcn_mfma_f32_16x16x32_bf16(af, bfr, acc[st], 0, 0, 0);
    }
  }
#pragma unroll
  for (int st = 0; st < 4; ++st) {
#pragma unroll
    for (int r = 0; r < 4; ++r) {
      const float val = acc[st][r];
      const float gel = 0.5f * val * (1.0f + erff(val * 0.70710678118f));
      hb[(size_t)(m0 + w * 16 + (hi << 2) + r) * 512 + n0 + st * 16 + lo] = f2bf(gel);
    }
  }
}

// ---------------- GEMM2 [NTOK,512]@[512,128] + residual -> out
__global__ __launch_bounds__(256) void gemm2_k(
    const u16* __restrict__ hb, const u16* __restrict__ w2t,
    const float* __restrict__ b2, const float* __restrict__ xf,
    float* __restrict__ out) {
  __shared__ __align__(16) u16 xs[64][136];
  __shared__ __align__(16) u16 wt[64][136];
  const int tid = threadIdx.x;
  const int w = tid >> 6, lane = tid & 63;
  const int lo = lane & 15, hi = lane >> 4;
  const int m0 = blockIdx.x * 64, n0 = blockIdx.y * 64;
  f32x4 acc[4];
#pragma unroll
  for (int st = 0; st < 4; ++st) {
    const float bv = b2[n0 + st * 16 + lo];
    acc[st] = (f32x4){bv, bv, bv, bv};
  }
  for (int kc = 0; kc < 4; ++kc) {
    if (kc) __syncthreads();
    {
      const int r = tid >> 2, sg = tid & 3;
      const u16* src_x = &hb[(size_t)(m0 + r) * 512 + kc * 128 + sg * 32];
      const u16* src_w = &w2t[(size_t)(n0 + r) * 512 + kc * 128 + sg * 32];
#pragma unroll
      for (int j = 0; j < 4; ++j) {
        *reinterpret_cast<u16x8*>(&xs[r][sg * 32 + j * 8]) = *reinterpret_cast<const u16x8*>(&src_x[j * 8]);
        *reinterpret_cast<u16x8*>(&wt[r][sg * 32 + j * 8]) = *reinterpret_cast<const u16x8*>(&src_w[j * 8]);
      }
    }
    __syncthreads();
#pragma unroll
    for (int kk = 0; kk < 4; ++kk) {
      const bf16x8 af = *reinterpret_cast<const bf16x8*>(&xs[w * 16 + lo][kk * 32 + 8 * hi]);
#pragma unroll
      for (int st = 0; st < 4; ++st) {
        const bf16x8 bfr = *reinterpret_cast<const bf16x8*>(&wt[st * 16 + lo][kk * 32 + 8 * hi]);
        acc[st] = __builtin_amdgcn_mfma_f32_16x16x32_bf16(af, bfr, acc[st], 0, 0, 0);
      }
    }
  }
#pragma unroll
  for (int st = 0; st < 4; ++st) {
#pragma unroll
    for (int r = 0; r < 4; ++r) {
      const size_t idx = (size_t)(m0 + w * 16 + (hi << 2) + r) * CC + n0 + st * 16 + lo;
      out[idx] = xf[idx] + acc[st][r];
    }
  }
}

extern "C" void kernel_launch(void* const* d_in, const int* in_sizes, int n_in,
                              void* d_out, int out_size, void* d_ws, size_t ws_size,
                              hipStream_t stream) {
  (void)in_sizes; (void)n_in; (void)out_size; (void)ws_size;
  const float* x   = (const float*)d_in[0];
  const float* wq  = (const float*)d_in[1];
  const float* bq  = (const float*)d_in[2];
  const float* wk  = (const float*)d_in[3];
  const float* bk  = (const float*)d_in[4];
  const float* wv  = (const float*)d_in[5];
  const float* bv  = (const float*)d_in[6];
  const float* wo  = (const float*)d_in[7];
  const float* bo  = (const float*)d_in[8];
  const float* w1  = (const float*)d_in[9];
  const float* b1  = (const float*)d_in[10];
  const float* w2  = (const float*)d_in[11];
  const float* b2  = (const float*)d_in[12];
  const float* g1  = (const float*)d_in[13];
  const float* be1 = (const float*)d_in[14];
  const float* g2  = (const float*)d_in[15];
  const float* be2 = (const float*)d_in[16];
  float* out = (float*)d_out;

  char* p = (char*)d_ws;
  auto alloc = [&](size_t bytes) { char* r = p; p += (bytes + 255) & ~(size_t)255; return r; };
  float* xf  = (float*)alloc((size_t)NTOK * CC * 4);
  u16* xg    = (u16*)alloc((size_t)NTOK * CC * 2);   // also ybf (ln out)
  u16* qw    = (u16*)alloc((size_t)NTOK * CC * 2 + 4096);
  u16* kw    = (u16*)alloc((size_t)NTOK * CC * 2 + 4096);
  u16* vtw   = (u16*)alloc((size_t)CC * VTW_STRIDE * 2);
  u16* aow   = (u16*)alloc((size_t)NTOK * CC * 2);   // also aog
  u16* hb    = (u16*)alloc((size_t)NTOK * 512 * 2);
  float* po  = (float*)alloc((size_t)2 * NTOK * CC * 4);
  float* pl  = (float*)alloc((size_t)2 * 16 * S_GLB * 4);
  u16* wqkvt = (u16*)alloc(3 * 16384 * 2);
  u16* wot   = (u16*)alloc(16384 * 2);
  u16* w1t   = (u16*)alloc(65536 * 2);
  u16* w2t   = (u16*)alloc(65536 * 2);

  cvt_all_k<<<768, 256, 0, stream>>>(w1, w2, wq, wk, wv, wo, w1t, w2t, wqkvt, wot);

  win_gather_k<<<NTOK / 2, 256, 0, stream>>>(x, xg);
  qkv_gemm_k<0><<<dim3(NTOK / 64, 6), 256, 0, stream>>>(xg, wqkvt, bq, bk, bv, qw, kw, vtw);
  win_attn_k<<<256, 256, 0, stream>>>(qw, kw, vtw, aow);
  proj_gemm_k<0><<<dim3(NTOK / 64, 2), 256, 0, stream>>>(aow, wot, bo, nullptr, xf);

  ln_k<<<NTOK / 8, 128, 0, stream>>>(xf, g1, be1, xg);
  qkv_gemm_k<1><<<dim3(NTOK / 64, 6), 256, 0, stream>>>(xg, wqkvt, bq, bk, bv, qw, kw, vtw);
  glb_attn_k<<<dim3(S_GLB / 64, 16, 2), 256, 0, stream>>>(qw, kw, vtw, po, pl);
  combine_k<<<NTOK / 2, 256, 0, stream>>>(po, pl, aow);
  proj_gemm_k<1><<<dim3(NTOK / 64, 2), 256, 0, stream>>>(aow, wot, bo, xf, xf);

  ln_k<<<NTOK / 8, 128, 0, stream>>>(xf, g2, be2, xg);
  gemm1_k<<<dim3(NTOK / 64, 8), 256, 0, stream>>>(xg, w1t, b1, hb);
  gemm2_k<<<dim3(NTOK / 64, 2), 256, 0, stream>>>(hb, w2t, b2, xf, out);
}

// Round 8
// 111.368 us; speedup vs baseline: 1.2532x; 1.1071x over previous
//
#include <hip/hip_runtime.h>
#include <hip/hip_bf16.h>
#include <math.h>

#define NH 4
#define DK 32
#define CC 128
#define HW 56
#define SHIFT 3
#define NTOK 12544   // 4*56*56 == 256*49
#define S_GLB 3136
#define VTW_STRIDE 12608
#define SCALE_L2E 0.25503488f  // log2(e)/sqrt(32): exp2-domain softmax scale

typedef unsigned short u16;
typedef short bf16x8 __attribute__((ext_vector_type(8)));
typedef unsigned short u16x8 __attribute__((ext_vector_type(8)));
typedef float f32x4 __attribute__((ext_vector_type(4)));

static __device__ __forceinline__ u16 f2bf(float f) {
  unsigned int b = __builtin_bit_cast(unsigned int, f);
  return (u16)((b + 0x7FFFu + ((b >> 16) & 1u)) >> 16);
}
static __device__ __forceinline__ unsigned pk2bf(float a, float b) {
  unsigned r;
  asm("v_cvt_pk_bf16_f32 %0, %1, %2" : "=v"(r) : "v"(a), "v"(b));
  return r;
}
static __device__ __forceinline__ float fexp2(float x) {
  float r;
  asm("v_exp_f32 %0, %1" : "=v"(r) : "v"(x));
  return r;
}
static __device__ __forceinline__ void gload16(const void* g, void* l) {
  __builtin_amdgcn_global_load_lds(
      (const __attribute__((address_space(1))) unsigned int*)g,
      (__attribute__((address_space(3))) unsigned int*)l, 16, 0, 0);
}

// ---------------- prep: weight converts (blocks 0..767) + shift-gather (rest)
__global__ __launch_bounds__(256) void prep_k(
    const float* __restrict__ w1, const float* __restrict__ w2,
    const float* __restrict__ wq, const float* __restrict__ wk,
    const float* __restrict__ wv, const float* __restrict__ wo,
    const float* __restrict__ x,
    u16* __restrict__ w1t, u16* __restrict__ w2t,
    u16* __restrict__ wqkvt, u16* __restrict__ wot, u16* __restrict__ xg) {
  if (blockIdx.x < 768) {
    const int idx = blockIdx.x * 256 + threadIdx.x;
    if (idx < 65536) {            // w1 [128][512] -> w1t [512][128]
      const int c = idx >> 7, r = idx & 127;
      w1t[idx] = f2bf(w1[r * 512 + c]);
    } else if (idx < 131072) {    // w2 [512][128] -> w2t [128][512]
      const int o = idx - 65536;
      const int c = o / 512, r = o - c * 512;
      w2t[o] = f2bf(w2[r * 128 + c]);
    } else {                      // four 128x128 -> transposed
      const int o = idx - 131072;
      const int which = o >> 14, oo = o & 16383;
      const int c = oo >> 7, r = oo & 127;
      const float* src = (which == 0) ? wq : (which == 1) ? wk : (which == 2) ? wv : wo;
      u16* dst = (which < 3) ? (wqkvt + which * 16384) : wot;
      dst[oo] = f2bf(src[r * 128 + c]);
    }
  } else {
    const int bid = blockIdx.x - 768;
    const int t = bid * 2 + (threadIdx.x >> 7);
    const int c = threadIdx.x & 127;
    const int win = t / 49, tok = t % 49;
    const int b = win >> 6, wrem = win & 63;
    const int wi = wrem >> 3, wj = wrem & 7;
    const int i = tok / 7, j = tok % 7;
    int hh = wi * 7 + i + SHIFT; if (hh >= HW) hh -= HW;
    int ww = wj * 7 + j + SHIFT; if (ww >= HW) ww -= HW;
    xg[(size_t)t * CC + c] = f2bf(x[((size_t)(b * HW + hh) * HW + ww) * CC + c]);
  }
}

// ---------------- fused QKV GEMM. PATH 0: window layout, PATH 1: global layout.
template <int PATH>
__global__ __launch_bounds__(256) void qkv_gemm_k(
    const u16* __restrict__ xin, const u16* __restrict__ wqkvt,
    const float* __restrict__ bq, const float* __restrict__ bk,
    const float* __restrict__ bv,
    u16* __restrict__ qo, u16* __restrict__ ko, u16* __restrict__ vto) {
  __shared__ __align__(16) u16 xs[64][136];
  __shared__ __align__(16) u16 wt[64][136];
  const int tid = threadIdx.x;
  const int w = tid >> 6, lane = tid & 63;
  const int lo = lane & 15, hi = lane >> 4, hi4 = hi * 4;
  const int m0 = blockIdx.x * 64;
  const int widx = blockIdx.y >> 1;
  const int n0 = (blockIdx.y & 1) * 64;
  {
    const int r = tid >> 2, sg = tid & 3;
    const u16* sx = &xin[(size_t)(m0 + r) * CC + sg * 32];
    const u16* sw = &wqkvt[(size_t)widx * CC * CC + (size_t)(n0 + r) * CC + sg * 32];
#pragma unroll
    for (int j = 0; j < 4; ++j) {
      *reinterpret_cast<u16x8*>(&xs[r][sg * 32 + j * 8]) = *reinterpret_cast<const u16x8*>(&sx[j * 8]);
      *reinterpret_cast<u16x8*>(&wt[r][sg * 32 + j * 8]) = *reinterpret_cast<const u16x8*>(&sw[j * 8]);
    }
  }
  __syncthreads();
  if (widx < 2) {
    const float* bias = (widx == 0) ? bq : bk;
    u16* outp = (widx == 0) ? qo : ko;
    const float oscale = (widx == 0) ? SCALE_L2E : 1.0f;
    f32x4 acc[4];
#pragma unroll
    for (int st = 0; st < 4; ++st) {
      const float b_ = bias[n0 + st * 16 + lo];
      acc[st] = (f32x4){b_, b_, b_, b_};
    }
#pragma unroll
    for (int kk = 0; kk < 4; ++kk) {
      const bf16x8 af = *reinterpret_cast<const bf16x8*>(&xs[w * 16 + lo][kk * 32 + 8 * hi]);
#pragma unroll
      for (int st = 0; st < 4; ++st) {
        const bf16x8 bfr = *reinterpret_cast<const bf16x8*>(&wt[st * 16 + lo][kk * 32 + 8 * hi]);
        acc[st] = __builtin_amdgcn_mfma_f32_16x16x32_bf16(af, bfr, acc[st], 0, 0, 0);
      }
    }
#pragma unroll
    for (int r = 0; r < 4; ++r) {
      const int mm = m0 + w * 16 + hi4 + r;
      size_t rowbase, hstride;
      if (PATH == 0) {
        const int win = mm / 49, tok = mm - win * 49;
        rowbase = ((size_t)(win * 4) * 49 + tok) * DK;
        hstride = (size_t)49 * DK;
      } else {
        const int b = mm / S_GLB, s = mm - b * S_GLB;
        rowbase = ((size_t)(b * 4) * S_GLB + s) * DK;
        hstride = (size_t)S_GLB * DK;
      }
#pragma unroll
      for (int st = 0; st < 4; ++st) {
        const int c = n0 + st * 16 + lo, h = c >> 5, d = c & 31;
        outp[rowbase + (size_t)h * hstride + d] = f2bf(acc[st][r] * oscale);
      }
    }
  } else {
    f32x4 bias4;
#pragma unroll
    for (int r = 0; r < 4; ++r) bias4[r] = bv[n0 + w * 16 + hi4 + r];
    f32x4 acc[4];
#pragma unroll
    for (int st = 0; st < 4; ++st) acc[st] = bias4;
#pragma unroll
    for (int kk = 0; kk < 4; ++kk) {
      const bf16x8 af = *reinterpret_cast<const bf16x8*>(&wt[w * 16 + lo][kk * 32 + 8 * hi]);
#pragma unroll
      for (int st = 0; st < 4; ++st) {
        const bf16x8 bfr = *reinterpret_cast<const bf16x8*>(&xs[st * 16 + lo][kk * 32 + 8 * hi]);
        acc[st] = __builtin_amdgcn_mfma_f32_16x16x32_bf16(af, bfr, acc[st], 0, 0, 0);
      }
    }
#pragma unroll
    for (int st = 0; st < 4; ++st) {
      const int mm = m0 + st * 16 + lo;
#pragma unroll
      for (int r = 0; r < 4; ++r) {
        const int c = n0 + w * 16 + hi4 + r;
        if (PATH == 0) {
          vto[(size_t)c * VTW_STRIDE + mm] = f2bf(acc[st][r]);
        } else {
          const int b = mm / S_GLB, s = mm - b * S_GLB;
          vto[((size_t)b * CC + c) * S_GLB + s] = f2bf(acc[st][r]);
        }
      }
    }
  }
}

// ---------------- window attention: no-max exp2 softmax, l via ones-MFMA
__global__ __launch_bounds__(256) void win_attn_k(
    const u16* __restrict__ qw, const u16* __restrict__ kw,
    const u16* __restrict__ vtw, u16* __restrict__ aow) {
  __shared__ __align__(16) u16 psh[4][16][72];
  const int tid = threadIdx.x;
  const int wvi = tid >> 6, lane = tid & 63;
  const int lo = lane & 15, hi = lane >> 4, hi4 = hi * 4;
  const int wh = blockIdx.x * 4 + wvi;
  const int win = wh >> 2, hd = wh & 3;
  const f32x4 zero4 = {0.f, 0.f, 0.f, 0.f};
  bf16x8 ones;
#pragma unroll
  for (int j = 0; j < 8; ++j) ones[j] = (short)0x3F80;

  bf16x8 kf[4], vf[2][2];
#pragma unroll
  for (int st = 0; st < 4; ++st)
    kf[st] = *reinterpret_cast<const bf16x8*>(&kw[((size_t)wh * 49 + st * 16 + lo) * DK + 8 * hi]);
#pragma unroll
  for (int dst = 0; dst < 2; ++dst)
#pragma unroll
    for (int kch = 0; kch < 2; ++kch)
      vf[dst][kch] = *reinterpret_cast<const bf16x8*>(
          &vtw[(size_t)(hd * DK + dst * 16 + lo) * VTW_STRIDE + win * 49 + kch * 32 + 8 * hi]);

#pragma unroll
  for (int g = 0; g < 4; ++g) {
    const bf16x8 qf = *reinterpret_cast<const bf16x8*>(
        &qw[((size_t)wh * 49 + g * 16 + lo) * DK + 8 * hi]);
    f32x4 s4[4];
#pragma unroll
    for (int st = 0; st < 4; ++st) {
      s4[st] = __builtin_amdgcn_mfma_f32_16x16x32_bf16(kf[st], qf, zero4, 0, 0, 0);
#pragma unroll
      for (int r = 0; r < 4; ++r)
        if (st * 16 + hi4 + r >= 49) s4[st][r] = -1e30f;  // mask pad keys -> p=0
    }
#pragma unroll
    for (int st = 0; st < 4; ++st) {
      uint2 pk;
      pk.x = pk2bf(fexp2(s4[st][0]), fexp2(s4[st][1]));
      pk.y = pk2bf(fexp2(s4[st][2]), fexp2(s4[st][3]));
      *reinterpret_cast<uint2*>(&psh[wvi][lo][st * 16 + hi4]) = pk;
    }
    asm volatile("" ::: "memory");
    f32x4 acc0 = zero4, acc1 = zero4, lacc = zero4;
#pragma unroll
    for (int kch = 0; kch < 2; ++kch) {
      const bf16x8 pa = *reinterpret_cast<const bf16x8*>(&psh[wvi][lo][kch * 32 + 8 * hi]);
      acc0 = __builtin_amdgcn_mfma_f32_16x16x32_bf16(pa, vf[0][kch], acc0, 0, 0, 0);
      acc1 = __builtin_amdgcn_mfma_f32_16x16x32_bf16(pa, vf[1][kch], acc1, 0, 0, 0);
      lacc = __builtin_amdgcn_mfma_f32_16x16x32_bf16(pa, ones, lacc, 0, 0, 0);
    }
#pragma unroll
    for (int r = 0; r < 4; ++r) {
      const int qrow = g * 16 + hi4 + r;
      if (qrow < 49) {
        const float rl = 1.0f / lacc[r];
        const size_t tw = (size_t)win * 49 + qrow;
        aow[tw * CC + hd * DK + lo] = f2bf(acc0[r] * rl);
        aow[tw * CC + hd * DK + 16 + lo] = f2bf(acc1[r] * rl);
      }
    }
  }
}

// ---------------- global attention: split-K (z=2) + gload_lds + swizzles.
__global__ __launch_bounds__(256) void glb_attn_k(
    const u16* __restrict__ qg, const u16* __restrict__ kg,
    const u16* __restrict__ vtg, float* __restrict__ po, float* __restrict__ pl) {
  __shared__ __align__(16) u16 ksh[2][64][32];   // linear, conflict-free reads
  __shared__ __align__(16) u16 vtsh[2][32][64];  // content XOR-swizzled via source
  __shared__ __align__(16) u16 psh[4][16][64];   // XOR-swizzled write/read
  const int tid = threadIdx.x;
  const int w = tid >> 6, lane = tid & 63;
  const int lo = lane & 15, hi = lane >> 4, hi4 = hi * 4;
  const int bh = blockIdx.y;
  const int q0 = blockIdx.x * 64;
  const int sp = blockIdx.z;
  const int kt_beg = sp * 25;
  const int kt_end = sp ? 49 : 25;
  const f32x4 zero4 = {0.f, 0.f, 0.f, 0.f};
  bf16x8 ones;
#pragma unroll
  for (int j = 0; j < 8; ++j) ones[j] = (short)0x3F80;

  const bf16x8 qfrag = *reinterpret_cast<const bf16x8*>(
      &qg[((size_t)bh * S_GLB + q0 + w * 16 + lo) * DK + 8 * hi]);
  const u16* kg0 = kg + (size_t)bh * S_GLB * DK;
  const u16* vg0 = vtg + (size_t)bh * DK * S_GLB;

  const u16* ksrc = kg0 + (size_t)(w * 16 + (lane >> 2)) * DK + (lane & 3) * 8;
  const u16* vsrc = vg0 + (size_t)(w * 8 + (lane >> 3)) * S_GLB + ((lane & 7) ^ (lane >> 3)) * 8;
  u16* kdst0 = &ksh[0][w * 16][0]; u16* kdst1 = &ksh[1][w * 16][0];
  u16* vdst0 = &vtsh[0][w * 8][0]; u16* vdst1 = &vtsh[1][w * 8][0];

  f32x4 oacc0 = zero4, oacc1 = zero4, lacc = zero4;

  gload16(ksrc + (size_t)kt_beg * 64 * DK, kdst0);
  gload16(vsrc + (size_t)kt_beg * 64, vdst0);
  __syncthreads();

  char* const pbase = (char*)&psh[w][lo][0];
  char* const vbase0 = (char*)&vtsh[0][0][0];
  const unsigned swz = (unsigned)(lo & 7) << 4;

  for (int kt = kt_beg; kt < kt_end; ++kt) {
    const int cur = (kt - kt_beg) & 1;
    if (kt + 1 < kt_end) {  // issue next-tile DMA before compute (2-phase)
      gload16(ksrc + (size_t)(kt + 1) * 64 * DK, cur ? kdst0 : kdst1);
      gload16(vsrc + (size_t)(kt + 1) * 64, cur ? vdst0 : vdst1);
    }
    // S^T = K * Q^T
    f32x4 s4[4];
#pragma unroll
    for (int st = 0; st < 4; ++st) {
      const bf16x8 kfrag = *reinterpret_cast<const bf16x8*>(&ksh[cur][st * 16 + lo][8 * hi]);
      s4[st] = __builtin_amdgcn_mfma_f32_16x16x32_bf16(kfrag, qfrag, zero4, 0, 0, 0);
    }
    // p = exp2(s), pack to bf16, swizzled P store
#pragma unroll
    for (int st = 0; st < 4; ++st) {
      uint2 pk;
      pk.x = pk2bf(fexp2(s4[st][0]), fexp2(s4[st][1]));
      pk.y = pk2bf(fexp2(s4[st][2]), fexp2(s4[st][3]));
      *reinterpret_cast<uint2*>(pbase + (((unsigned)(st * 32 + hi * 8)) ^ swz)) = pk;
    }
    asm volatile("" ::: "memory");
    // PV + l via ones-MFMA
    char* const vrow0 = vbase0 + (size_t)cur * (32 * 64 * 2) + lo * 128;
#pragma unroll
    for (int kch = 0; kch < 2; ++kch) {
      const unsigned off = ((unsigned)(kch * 64 + hi * 16)) ^ swz;
      const bf16x8 pa = *reinterpret_cast<const bf16x8*>(pbase + off);
      const bf16x8 v0 = *reinterpret_cast<const bf16x8*>(vrow0 + off);
      const bf16x8 v1 = *reinterpret_cast<const bf16x8*>(vrow0 + 16 * 128 + off);
      oacc0 = __builtin_amdgcn_mfma_f32_16x16x32_bf16(pa, v0, oacc0, 0, 0, 0);
      oacc1 = __builtin_amdgcn_mfma_f32_16x16x32_bf16(pa, v1, oacc1, 0, 0, 0);
      lacc = __builtin_amdgcn_mfma_f32_16x16x32_bf16(pa, ones, lacc, 0, 0, 0);
    }
    __syncthreads();  // drains vmcnt: next tile landed; cur free to overwrite
  }

  const int b = bh >> 2, hd = bh & 3;
  float* pob = po + (size_t)sp * NTOK * CC;
#pragma unroll
  for (int r = 0; r < 4; ++r) {
    const size_t t = (size_t)b * S_GLB + q0 + w * 16 + hi4 + r;
    pob[t * CC + hd * DK + lo] = oacc0[r];
    pob[t * CC + hd * DK + 16 + lo] = oacc1[r];
    if (lo == 0)
      pl[((size_t)sp * 16 + bh) * S_GLB + q0 + w * 16 + hi4 + r] = lacc[r];
  }
}

// ---------------- output projection GEMM with FUSED LayerNorm epilogue.
// Full N=128 per block (LN needs complete rows). 64 rows/block, 4 waves.
// MODE 0: input aow bf16; scatter rows via window-reverse; xf = proj,
//         ybf = LN1(proj).
// MODE 1: input = split-K partials (combine in staging); rows identity;
//         xf = resid + proj, ybf = LN2(xf).
template <int MODE>
__global__ __launch_bounds__(256) void proj_ln_k(
    const u16* __restrict__ ain, const float* __restrict__ po,
    const float* __restrict__ pl, const u16* __restrict__ wot,
    const float* __restrict__ bo, const float* __restrict__ resid,
    const float* __restrict__ lng, const float* __restrict__ lnb,
    float* __restrict__ xfo, u16* __restrict__ ybf) {
  __shared__ __align__(16) u16 xs[64][136];
  __shared__ __align__(16) u16 wt[128][136];
  const int tid = threadIdx.x;
  const int w = tid >> 6, lane = tid & 63;
  const int lo = lane & 15, hi = lane >> 4, hi4 = hi * 4;
  const int m0 = blockIdx.x * 64;
  {
    const int r = tid >> 2, sg = tid & 3;
    if (MODE == 0) {
      const u16* sx = &ain[(size_t)(m0 + r) * CC + sg * 32];
#pragma unroll
      for (int j = 0; j < 4; ++j)
        *reinterpret_cast<u16x8*>(&xs[r][sg * 32 + j * 8]) = *reinterpret_cast<const u16x8*>(&sx[j * 8]);
    } else {
      // fused split-K combine: head == sg (32 channels/head)
      const int mm = m0 + r;
      const int b = mm / S_GLB, s_ = mm - b * S_GLB;
      const float l0 = pl[((size_t)(b * 4 + sg)) * S_GLB + s_];
      const float l1 = pl[((size_t)(16 + b * 4 + sg)) * S_GLB + s_];
      const float rl = 1.0f / (l0 + l1);
      const float* pa = &po[(size_t)mm * CC + sg * 32];
      const float* pb = pa + (size_t)NTOK * CC;
#pragma unroll
      for (int j = 0; j < 32; j += 4) {
        const float4 a4 = *reinterpret_cast<const float4*>(&pa[j]);
        const float4 b4 = *reinterpret_cast<const float4*>(&pb[j]);
        uint2 pk;
        pk.x = pk2bf((a4.x + b4.x) * rl, (a4.y + b4.y) * rl);
        pk.y = pk2bf((a4.z + b4.z) * rl, (a4.w + b4.w) * rl);
        *reinterpret_cast<uint2*>(&xs[r][sg * 32 + j]) = pk;
      }
    }
    // weights: 128 rows x 128 cols
    const int r2 = tid >> 1, sg2 = tid & 1;
    const u16* sw = &wot[(size_t)r2 * CC + sg2 * 64];
#pragma unroll
    for (int j = 0; j < 8; ++j)
      *reinterpret_cast<u16x8*>(&wt[r2][sg2 * 64 + j * 8]) = *reinterpret_cast<const u16x8*>(&sw[j * 8]);
  }
  __syncthreads();
  f32x4 acc[8];
#pragma unroll
  for (int st = 0; st < 8; ++st) {
    const float b_ = bo[st * 16 + lo];
    acc[st] = (f32x4){b_, b_, b_, b_};
  }
#pragma unroll
  for (int kk = 0; kk < 4; ++kk) {
    const bf16x8 af = *reinterpret_cast<const bf16x8*>(&xs[w * 16 + lo][kk * 32 + 8 * hi]);
#pragma unroll
    for (int st = 0; st < 8; ++st) {
      const bf16x8 bfr = *reinterpret_cast<const bf16x8*>(&wt[st * 16 + lo][kk * 32 + 8 * hi]);
      acc[st] = __builtin_amdgcn_mfma_f32_16x16x32_bf16(af, bfr, acc[st], 0, 0, 0);
    }
  }
  float gv[8], bv2[8];
#pragma unroll
  for (int st = 0; st < 8; ++st) { gv[st] = lng[st * 16 + lo]; bv2[st] = lnb[st * 16 + lo]; }
#pragma unroll
  for (int r = 0; r < 4; ++r) {
    const int mm = m0 + w * 16 + hi4 + r;
    size_t trow;
    if (MODE == 0) {
      const int win = mm / 49, tok = mm - win * 49;
      const int b = win >> 6, wi = (win >> 3) & 7, wj = win & 7;
      const int ii = tok / 7, jj = tok - ii * 7;
      int hr = wi * 7 + ii + SHIFT; if (hr >= HW) hr -= HW;
      int wr = wj * 7 + jj + SHIFT; if (wr >= HW) wr -= HW;
      trow = (size_t)b * S_GLB + hr * HW + wr;
    } else {
      trow = (size_t)mm;
    }
    float v[8];
    float s = 0.f, sq = 0.f;
#pragma unroll
    for (int st = 0; st < 8; ++st) {
      float t_ = acc[st][r];
      if (MODE == 1) t_ += resid[trow * CC + st * 16 + lo];
      v[st] = t_;
      s += t_;
      sq += t_ * t_;
    }
    s += __shfl_xor(s, 1); s += __shfl_xor(s, 2); s += __shfl_xor(s, 4); s += __shfl_xor(s, 8);
    sq += __shfl_xor(sq, 1); sq += __shfl_xor(sq, 2); sq += __shfl_xor(sq, 4); sq += __shfl_xor(sq, 8);
    const float mu = s * 0.0078125f;
    const float rsig = rsqrtf(sq * 0.0078125f - mu * mu + 1e-5f);
#pragma unroll
    for (int st = 0; st < 8; ++st) {
      const size_t idx = trow * CC + st * 16 + lo;
      xfo[idx] = v[st];
      ybf[idx] = f2bf((v[st] - mu) * rsig * gv[st] + bv2[st]);
    }
  }
}

// ---------------- GEMM1 [NTOK,128]@[128,512] + gelu -> bf16
__global__ __launch_bounds__(256) void gemm1_k(
    const u16* __restrict__ ybf, const u16* __restrict__ w1t,
    const float* __restrict__ b1, u16* __restrict__ hb) {
  __shared__ __align__(16) u16 xs[64][136];
  __shared__ __align__(16) u16 wt[64][136];
  const int tid = threadIdx.x;
  const int w = tid >> 6, lane = tid & 63;
  const int lo = lane & 15, hi = lane >> 4;
  const int m0 = blockIdx.x * 64, n0 = blockIdx.y * 64;
  {
    const int r = tid >> 2, sg = tid & 3;
    const u16* src_x = &ybf[(size_t)(m0 + r) * CC + sg * 32];
    const u16* src_w = &w1t[(size_t)(n0 + r) * CC + sg * 32];
#pragma unroll
    for (int j = 0; j < 4; ++j) {
      *reinterpret_cast<u16x8*>(&xs[r][sg * 32 + j * 8]) = *reinterpret_cast<const u16x8*>(&src_x[j * 8]);
      *reinterpret_cast<u16x8*>(&wt[r][sg * 32 + j * 8]) = *reinterpret_cast<const u16x8*>(&src_w[j * 8]);
    }
  }
  __syncthreads();
  f32x4 acc[4];
#pragma unroll
  for (int st = 0; st < 4; ++st) {
    const float bv = b1[n0 + st * 16 + lo];
    acc[st] = (f32x4){bv, bv, bv, bv};
  }
#pragma unroll
  for (int kk = 0; kk < 4; ++kk) {
    const bf16x8 af = *reinterpret_cast<const bf16x8*>(&xs[w * 16 + lo][kk * 32 + 8 * hi]);
#pragma unroll
    for (int st = 0; st < 4; ++st) {
      const bf16x8 bfr = *reinterpret_cast<const bf16x8*>(&wt[st * 16 + lo][kk * 32 + 8 * hi]);
      acc[st] = __builtin_amdgcn_mfma_f32_16x16x32_bf16(af, bfr, acc[st], 0, 0, 0);
    }
  }
#pragma unroll
  for (int st = 0; st < 4; ++st) {
#pragma unroll
    for (int r = 0; r < 4; ++r) {
      const float val = acc[st][r];
      const float gel = 0.5f * val * (1.0f + erff(val * 0.70710678118f));
      hb[(size_t)(m0 + w * 16 + (hi << 2) + r) * 512 + n0 + st * 16 + lo] = f2bf(gel);
    }
  }
}

// ---------------- GEMM2 [NTOK,512]@[512,128] + residual -> out
__global__ __launch_bounds__(256) void gemm2_k(
    const u16* __restrict__ hb, const u16* __restrict__ w2t,
    const float* __restrict__ b2, const float* __restrict__ xf,
    float* __restrict__ out) {
  __shared__ __align__(16) u16 xs[64][136];
  __shared__ __align__(16) u16 wt[64][136];
  const int tid = threadIdx.x;
  const int w = tid >> 6, lane = tid & 63;
  const int lo = lane & 15, hi = lane >> 4;
  const int m0 = blockIdx.x * 64, n0 = blockIdx.y * 64;
  f32x4 acc[4];
#pragma unroll
  for (int st = 0; st < 4; ++st) {
    const float bv = b2[n0 + st * 16 + lo];
    acc[st] = (f32x4){bv, bv, bv, bv};
  }
  for (int kc = 0; kc < 4; ++kc) {
    if (kc) __syncthreads();
    {
      const int r = tid >> 2, sg = tid & 3;
      const u16* src_x = &hb[(size_t)(m0 + r) * 512 + kc * 128 + sg * 32];
      const u16* src_w = &w2t[(size_t)(n0 + r) * 512 + kc * 128 + sg * 32];
#pragma unroll
      for (int j = 0; j < 4; ++j) {
        *reinterpret_cast<u16x8*>(&xs[r][sg * 32 + j * 8]) = *reinterpret_cast<const u16x8*>(&src_x[j * 8]);
        *reinterpret_cast<u16x8*>(&wt[r][sg * 32 + j * 8]) = *reinterpret_cast<const u16x8*>(&src_w[j * 8]);
      }
    }
    __syncthreads();
#pragma unroll
    for (int kk = 0; kk < 4; ++kk) {
      const bf16x8 af = *reinterpret_cast<const bf16x8*>(&xs[w * 16 + lo][kk * 32 + 8 * hi]);
#pragma unroll
      for (int st = 0; st < 4; ++st) {
        const bf16x8 bfr = *reinterpret_cast<const bf16x8*>(&wt[st * 16 + lo][kk * 32 + 8 * hi]);
        acc[st] = __builtin_amdgcn_mfma_f32_16x16x32_bf16(af, bfr, acc[st], 0, 0, 0);
      }
    }
  }
#pragma unroll
  for (int st = 0; st < 4; ++st) {
#pragma unroll
    for (int r = 0; r < 4; ++r) {
      const size_t idx = (size_t)(m0 + w * 16 + (hi << 2) + r) * CC + n0 + st * 16 + lo;
      out[idx] = xf[idx] + acc[st][r];
    }
  }
}

extern "C" void kernel_launch(void* const* d_in, const int* in_sizes, int n_in,
                              void* d_out, int out_size, void* d_ws, size_t ws_size,
                              hipStream_t stream) {
  (void)in_sizes; (void)n_in; (void)out_size; (void)ws_size;
  const float* x   = (const float*)d_in[0];
  const float* wq  = (const float*)d_in[1];
  const float* bq  = (const float*)d_in[2];
  const float* wk  = (const float*)d_in[3];
  const float* bk  = (const float*)d_in[4];
  const float* wv  = (const float*)d_in[5];
  const float* bv  = (const float*)d_in[6];
  const float* wo  = (const float*)d_in[7];
  const float* bo  = (const float*)d_in[8];
  const float* w1  = (const float*)d_in[9];
  const float* b1  = (const float*)d_in[10];
  const float* w2  = (const float*)d_in[11];
  const float* b2  = (const float*)d_in[12];
  const float* g1  = (const float*)d_in[13];
  const float* be1 = (const float*)d_in[14];
  const float* g2  = (const float*)d_in[15];
  const float* be2 = (const float*)d_in[16];
  float* out = (float*)d_out;

  char* p = (char*)d_ws;
  auto alloc = [&](size_t bytes) { char* r = p; p += (bytes + 255) & ~(size_t)255; return r; };
  float* xf  = (float*)alloc((size_t)NTOK * CC * 4);
  u16* xg    = (u16*)alloc((size_t)NTOK * CC * 2);   // gather out / LN out (ybf)
  u16* qw    = (u16*)alloc((size_t)NTOK * CC * 2 + 4096);
  u16* kw    = (u16*)alloc((size_t)NTOK * CC * 2 + 4096);
  u16* vtw   = (u16*)alloc((size_t)CC * VTW_STRIDE * 2);
  u16* aow   = (u16*)alloc((size_t)NTOK * CC * 2);
  u16* hb    = (u16*)alloc((size_t)NTOK * 512 * 2);
  float* po  = (float*)alloc((size_t)2 * NTOK * CC * 4);
  float* pl  = (float*)alloc((size_t)2 * 16 * S_GLB * 4);
  u16* wqkvt = (u16*)alloc(3 * 16384 * 2);
  u16* wot   = (u16*)alloc(16384 * 2);
  u16* w1t   = (u16*)alloc(65536 * 2);
  u16* w2t   = (u16*)alloc(65536 * 2);

  prep_k<<<768 + NTOK / 2, 256, 0, stream>>>(
      w1, w2, wq, wk, wv, wo, x, w1t, w2t, wqkvt, wot, xg);
  qkv_gemm_k<0><<<dim3(NTOK / 64, 6), 256, 0, stream>>>(xg, wqkvt, bq, bk, bv, qw, kw, vtw);
  win_attn_k<<<256, 256, 0, stream>>>(qw, kw, vtw, aow);
  proj_ln_k<0><<<NTOK / 64, 256, 0, stream>>>(
      aow, nullptr, nullptr, wot, bo, nullptr, g1, be1, xf, xg);
  qkv_gemm_k<1><<<dim3(NTOK / 64, 6), 256, 0, stream>>>(xg, wqkvt, bq, bk, bv, qw, kw, vtw);
  glb_attn_k<<<dim3(S_GLB / 64, 16, 2), 256, 0, stream>>>(qw, kw, vtw, po, pl);
  proj_ln_k<1><<<NTOK / 64, 256, 0, stream>>>(
      nullptr, po, pl, wot, bo, xf, g2, be2, xf, xg);
  gemm1_k<<<dim3(NTOK / 64, 8), 256, 0, stream>>>(xg, w1t, b1, hb);
  gemm2_k<<<dim3(NTOK / 64, 2), 256, 0, stream>>>(hb, w2t, b2, xf, out);
}